// Round 8
// baseline (914.948 us; speedup 1.0000x reference)
//
#include <hip/hip_runtime.h>
#include <hip/hip_bf16.h>
#include <stdint.h>

#define N_TOK 8192
#define CDIM  1024
#define HDIM  4096
#define NEXP  8
#define BM    128
#define BN    128
#define BK    32

typedef __attribute__((ext_vector_type(8))) short bf16x8;
typedef __attribute__((ext_vector_type(4))) float f32x4;

static __device__ __forceinline__ uint16_t f2bf(float f) {
  union { float f; uint32_t u; } v; v.f = f;
  uint32_t r = v.u + 0x7FFF + ((v.u >> 16) & 1);
  return (uint16_t)(r >> 16);
}

__device__ __forceinline__ void gload_lds16(const void* g, void* l) {
  __builtin_amdgcn_global_load_lds(
      (const __attribute__((address_space(1))) uint32_t*)g,
      (__attribute__((address_space(3))) uint32_t*)l, 16, 0, 0);
}

// ------- transpose+convert: src [R][S] f32 -> dst [S][R] bf16; 128(r)x64(c) tile -------
__global__ void transcvt_kernel(const float* __restrict__ src, uint16_t* __restrict__ dst,
                                int R, int S) {
  __shared__ float tile[128 * 64];
  size_t base = (size_t)blockIdx.z * (size_t)R * S;
  int c0 = blockIdx.x * 64, r0 = blockIdx.y * 128;
  int t = threadIdx.x;
#pragma unroll
  for (int q = 0; q < 8; q++) {
    int idx = q * 256 + t;
    int row = idx >> 4, s = idx & 15;
    float4 v = *(const float4*)&src[base + (size_t)(r0 + row) * S + c0 + s * 4];
    *(float4*)&tile[row * 64 + ((s ^ ((row >> 3) & 15)) << 2)] = v;
  }
  __syncthreads();
#pragma unroll
  for (int q = 0; q < 4; q++) {
    int idx = q * 256 + t;
    int crow = idx >> 4, r8 = (idx & 15) * 8;
    bf16x8 o;
#pragma unroll
    for (int k = 0; k < 8; k++) {
      int r = r8 + k;
      o[k] = (short)f2bf(tile[r * 64 + (((crow >> 2) ^ ((r >> 3) & 15)) << 2) + (crow & 3)]);
    }
    *(bf16x8*)&dst[base + (size_t)(c0 + crow) * R + r0 + r8] = o;
  }
}

// ---------------- router (+ fused x->bf16): one wave per token ----------------
__global__ void router_kernel(const float* __restrict__ x, const float* __restrict__ Wr,
                              int* __restrict__ cnt, int* __restrict__ te,
                              float* __restrict__ tw, uint16_t* __restrict__ xb) {
  int wid = (blockIdx.x * blockDim.x + threadIdx.x) >> 6;
  int lane = threadIdx.x & 63;
  if (wid >= N_TOK) return;
  const float* xr = x + (size_t)wid * CDIM;
  uint16_t* xbr = xb + (size_t)wid * CDIM;
  float p[NEXP];
#pragma unroll
  for (int e = 0; e < NEXP; e++) p[e] = 0.f;
  for (int kk = 0; kk < CDIM / 64; kk++) {
    float xv = xr[kk * 64 + lane];
    xbr[kk * 64 + lane] = f2bf(xv);
#pragma unroll
    for (int e = 0; e < NEXP; e++)
      p[e] += xv * Wr[e * CDIM + kk * 64 + lane];
  }
#pragma unroll
  for (int e = 0; e < NEXP; e++) {
    float v = p[e];
#pragma unroll
    for (int s = 32; s > 0; s >>= 1) v += __shfl_xor(v, s);
    p[e] = v;
  }
  if (lane == 0) {
    float m0 = -1e30f, m1 = -1e30f; int i0 = 0, i1 = 0;
#pragma unroll
    for (int e = 0; e < NEXP; e++) {
      float v = p[e];
      if (v > m0) { m1 = m0; i1 = i0; m0 = v; i0 = e; }
      else if (v > m1) { m1 = v; i1 = e; }
    }
    float w0 = 1.f / (1.f + __expf(m1 - m0));
    te[wid] = i0 | (i1 << 16);
    tw[wid] = w0;
    atomicAdd(&cnt[i0], 1);
    atomicAdd(&cnt[i1], 1);
  }
}

// ---- prefix + compact work-list: wk[i] = (e<<16)|rb_block for every active 128-row block ----
__global__ void prefix_kernel(const int* __restrict__ cnt, int* __restrict__ offs,
                              int* __restrict__ fill, int* __restrict__ wk,
                              int* __restrict__ nwk) {
  if (threadIdx.x == 0) {
    int acc = 0, np = 0;
    for (int e = 0; e < NEXP; e++) {
      offs[e] = acc; fill[e] = acc;
      int nb = (cnt[e] + BM - 1) / BM;
      for (int r = 0; r < nb; r++) wk[np++] = (e << 16) | r;
      acc += cnt[e];
    }
    offs[NEXP] = acc;
    nwk[0] = np;
  }
}

__global__ void bucket_kernel(const int* __restrict__ te, const float* __restrict__ tw,
                              int* __restrict__ fill, int* __restrict__ perm,
                              float* __restrict__ pw) {
  int t = blockIdx.x * 256 + threadIdx.x;
  if (t >= N_TOK) return;
  int e01 = te[t];
  int e0 = e01 & 0xffff, e1 = e01 >> 16;
  float w0 = tw[t];
  int p0 = atomicAdd(&fill[e0], 1);
  perm[p0] = t; pw[p0] = w0;
  int p1 = atomicAdd(&fill[e1], 1);
  perm[p1] = t; pw[p1] = 1.f - w0;
}

// ---- grouped GEMM: 128x128, BK=32, 4 waves, dbuf 32KB LDS -> 5 blocks/CU.
// ---- Lean counted-vmcnt loop: STAGE(next) -> vmcnt(4) (prev tile retired, new 4 fly
// ---- under compute) -> s_barrier -> free-running reads+MFMA -> s_barrier. Never drains
// ---- to 0 mid-loop. XOR swizzle slot^(row&3) on source + frag reads (2-way = free).
template<bool GATHER, bool RELU2, int NDIM, int KDIM>
__global__ __launch_bounds__(256, 5)
void moe_gemm(const uint16_t* __restrict__ A, const uint16_t* __restrict__ Bt,
              const int* __restrict__ offs, const int* __restrict__ wk,
              const int* __restrict__ nwk, const int* __restrict__ perm,
              const float* __restrict__ pw, uint16_t* __restrict__ hb,
              float* __restrict__ out) {
  const int NB = NDIM / BN;
  int nitems = nwk[0] * NB;
  int G = gridDim.x;
  int bid = blockIdx.x;
  int b0 = (bid & 7) * (G >> 3) + (bid >> 3);   // XCD gets contiguous item chunk

  __shared__ uint16_t smA[2][BM * BK];   // 2 x 8KB
  __shared__ uint16_t smB[2][BN * BK];   // 2 x 8KB   (32KB total)

  int tid = threadIdx.x;
  int w = tid >> 6, l = tid & 63;
  int wr = w >> 1, wc = w & 1;           // 2x2 waves, wave tile 64x64
  int cl = l & 15, kq = l >> 4;
  int rg = kq * 4;

  for (int item = b0; item < nitems; item += G) {
    int pi = item / NB, nb = item - pi * NB;
    int pr = wk[pi];
    int e = pr >> 16;
    int rb = (pr & 0xffff) * BM;
    int o0 = offs[e];
    int Me = offs[e + 1] - o0;
    int nb0 = nb * BN;

    // staging pointers: chunk c = j*256+tid -> row = c>>2, slot16B = c&3;
    // source k-chunk = (slot ^ (row&3)) (XOR swizzle folded into source, linear LDS dest)
    const uint16_t* aptr[2];
#pragma unroll
    for (int j = 0; j < 2; j++) {
      int c = j * 256 + tid;
      int row = c >> 2, slot = c & 3;
      int gi = o0 + rb + row;
      if (gi > 2 * N_TOK - 1) gi = 2 * N_TOK - 1;
      int ar = GATHER ? perm[gi] : gi;
      aptr[j] = A + (size_t)ar * KDIM + ((slot ^ (row & 3)) << 3);
    }
    const uint16_t* bb = Bt + (size_t)e * NDIM * KDIM;
    const uint16_t* bptr[2];
#pragma unroll
    for (int j = 0; j < 2; j++) {
      int c = j * 256 + tid;
      int row = c >> 2, slot = c & 3;
      bptr[j] = bb + (size_t)(nb0 + row) * KDIM + ((slot ^ (row & 3)) << 3);
    }

    f32x4 acc[4][4];
#pragma unroll
    for (int m = 0; m < 4; m++)
#pragma unroll
      for (int n = 0; n < 4; n++)
        acc[m][n] = (f32x4)0.f;

#define STG(bi, kt) do {                                                     \
      gload_lds16(aptr[0] + (kt) * BK, (char*)&smA[bi][0] + tid * 16);       \
      gload_lds16(aptr[1] + (kt) * BK, (char*)&smA[bi][0] + 4096 + tid * 16);\
      gload_lds16(bptr[0] + (kt) * BK, (char*)&smB[bi][0] + tid * 16);       \
      gload_lds16(bptr[1] + (kt) * BK, (char*)&smB[bi][0] + 4096 + tid * 16);\
    } while (0)

    // swizzled frag read: 16B slot s XOR'd by row&3
#define LDSF(base, row, s) \
    (*(const bf16x8*)&(base)[(row) * BK + ((((s) ^ ((row) & 3))) << 3)])

    const int NT = KDIM / BK;
    STG(0, 0);                            // 4 loads in flight; t=0's vmcnt+barrier covers
    for (int t = 0; t < NT; ++t) {
      int cur = t & 1;
      if (t + 1 < NT) {
        STG(cur ^ 1, t + 1);              // overwrite buf last read at t-1 (safe: end
                                          // barrier of t-1); these 4 fly under compute
        asm volatile("s_waitcnt vmcnt(4)" ::: "memory");   // prev-tile stage landed
      } else {
        asm volatile("s_waitcnt vmcnt(0)" ::: "memory");
      }
      asm volatile("s_barrier" ::: "memory");   // all slices of buf[cur] landed

      const uint16_t* sA = &smA[cur][0];
      const uint16_t* sB = &smB[cur][0];
      bf16x8 af[4], bf[4];
#pragma unroll
      for (int n = 0; n < 4; n++)
        bf[n] = LDSF(sB, wc * 64 + n * 16 + cl, kq);
#pragma unroll
      for (int m = 0; m < 4; m++)
        af[m] = LDSF(sA, wr * 64 + m * 16 + cl, kq);
#pragma unroll
      for (int m = 0; m < 4; m++)
#pragma unroll
        for (int n = 0; n < 4; n++)
          acc[m][n] = __builtin_amdgcn_mfma_f32_16x16x32_bf16(af[m], bf[n], acc[m][n], 0, 0, 0);
      asm volatile("s_barrier" ::: "memory");   // reads of buf[cur] done; next iter
                                                // (or next item) may overwrite it
    }
#undef STG
#undef LDSF

    if (RELU2) {
#pragma unroll
      for (int m = 0; m < 4; m++) {
#pragma unroll
        for (int jj = 0; jj < 4; jj++) {
          int er = rb + wr * 64 + m * 16 + rg + jj;
          if (er < Me) {
            size_t rowoff = (size_t)(o0 + er) * NDIM;
#pragma unroll
            for (int n = 0; n < 4; n++) {
              int gc = nb0 + wc * 64 + n * 16 + cl;
              float v = acc[m][n][jj];
              v = v > 0.f ? v * v : 0.f;
              hb[rowoff + gc] = f2bf(v);
            }
          }
        }
      }
    } else {
#pragma unroll
      for (int m = 0; m < 4; m++) {
#pragma unroll
        for (int jj = 0; jj < 4; jj++) {
          int er = rb + wr * 64 + m * 16 + rg + jj;
          if (er < Me) {
            int gi = o0 + er;
            int tok = perm[gi];
            float wgt = pw[gi];
            size_t rowoff = (size_t)tok * NDIM;
#pragma unroll
            for (int n = 0; n < 4; n++) {
              int gc = nb0 + wc * 64 + n * 16 + cl;
              atomicAdd(&out[rowoff + gc], wgt * acc[m][n][jj]);
            }
          }
        }
      }
    }
  }
}

extern "C" void kernel_launch(void* const* d_in, const int* in_sizes, int n_in,
                              void* d_out, int out_size, void* d_ws, size_t ws_size,
                              hipStream_t stream) {
  const float* x  = (const float*)d_in[0];
  const float* Wr = (const float*)d_in[1];
  const float* W1 = (const float*)d_in[2];
  const float* W2 = (const float*)d_in[3];
  float* out = (float*)d_out;

  char* ws = (char*)d_ws;
  size_t off = 0;
  uint16_t* xb  = (uint16_t*)(ws + off); off += (size_t)N_TOK * CDIM * 2;
  uint16_t* W1t = (uint16_t*)(ws + off); off += (size_t)NEXP * CDIM * HDIM * 2;
  uint16_t* W2t = (uint16_t*)(ws + off); off += (size_t)NEXP * CDIM * HDIM * 2;
  uint16_t* hb  = (uint16_t*)(ws + off); off += (size_t)2 * N_TOK * HDIM * 2;
  int*   perm = (int*)(ws + off); off += (size_t)2 * N_TOK * 4;
  float* pwt  = (float*)(ws + off); off += (size_t)2 * N_TOK * 4;
  int*   te   = (int*)(ws + off); off += (size_t)N_TOK * 4;
  float* tw   = (float*)(ws + off); off += (size_t)N_TOK * 4;
  int*   cnt  = (int*)(ws + off); off += 16 * 4;
  int*   offs = (int*)(ws + off); off += 16 * 4;
  int*   fill = (int*)(ws + off); off += 16 * 4;
  int*   wk   = (int*)(ws + off); off += 256 * 4;
  int*   nwk  = (int*)(ws + off); off += 16 * 4;

  hipMemsetAsync(d_out, 0, (size_t)out_size * sizeof(float), stream);
  hipMemsetAsync(cnt, 0, 16 * 4, stream);

  router_kernel<<<N_TOK / 4, 256, 0, stream>>>(x, Wr, cnt, te, tw, xb);
  transcvt_kernel<<<dim3(HDIM / 64, CDIM / 128, NEXP), 256, 0, stream>>>(W1, W1t, CDIM, HDIM);
  transcvt_kernel<<<dim3(CDIM / 64, HDIM / 128, NEXP), 256, 0, stream>>>(W2, W2t, HDIM, CDIM);
  prefix_kernel<<<1, 64, 0, stream>>>(cnt, offs, fill, wk, nwk);
  bucket_kernel<<<N_TOK / 256, 256, 0, stream>>>(te, tw, fill, perm, pwt);

  // GEMM1: h = relu^2(x @ W1)  [rows gathered via perm]  items = 128*32 = 4096, 2/block
  moe_gemm<true, true, HDIM, CDIM><<<2048, 256, 0, stream>>>(
      xb, W1t, offs, wk, nwk, perm, pwt, hb, out);
  // GEMM2: out += gate * (h @ W2)   items = 128*8 = 1024, 1/block
  moe_gemm<false, false, CDIM, HDIM><<<1024, 256, 0, stream>>>(
      hb, W2t, offs, wk, nwk, perm, pwt, hb, out);
}

// Round 9
// 750.663 us; speedup vs baseline: 1.2189x; 1.2189x over previous
//
#include <hip/hip_runtime.h>
#include <hip/hip_bf16.h>
#include <stdint.h>

#define N_TOK 8192
#define CDIM  1024
#define HDIM  4096
#define NEXP  8
#define BM    128
#define BN    128
#define BK    64

typedef __attribute__((ext_vector_type(8))) short bf16x8;
typedef __attribute__((ext_vector_type(4))) float f32x4;

static __device__ __forceinline__ uint16_t f2bf(float f) {
  union { float f; uint32_t u; } v; v.f = f;
  uint32_t r = v.u + 0x7FFF + ((v.u >> 16) & 1);
  return (uint16_t)(r >> 16);
}

__device__ __forceinline__ void gload_lds16(const void* g, void* l) {
  __builtin_amdgcn_global_load_lds(
      (const __attribute__((address_space(1))) uint32_t*)g,
      (__attribute__((address_space(3))) uint32_t*)l, 16, 0, 0);
}

// ------- transpose+convert: src [R][S] f32 -> dst [S][R] bf16; 128(r)x64(c) tile -------
__global__ void transcvt_kernel(const float* __restrict__ src, uint16_t* __restrict__ dst,
                                int R, int S) {
  __shared__ float tile[128 * 64];
  size_t base = (size_t)blockIdx.z * (size_t)R * S;
  int c0 = blockIdx.x * 64, r0 = blockIdx.y * 128;
  int t = threadIdx.x;
#pragma unroll
  for (int q = 0; q < 8; q++) {
    int idx = q * 256 + t;
    int row = idx >> 4, s = idx & 15;
    float4 v = *(const float4*)&src[base + (size_t)(r0 + row) * S + c0 + s * 4];
    *(float4*)&tile[row * 64 + ((s ^ ((row >> 3) & 15)) << 2)] = v;
  }
  __syncthreads();
#pragma unroll
  for (int q = 0; q < 4; q++) {
    int idx = q * 256 + t;
    int crow = idx >> 4, r8 = (idx & 15) * 8;
    bf16x8 o;
#pragma unroll
    for (int k = 0; k < 8; k++) {
      int r = r8 + k;
      o[k] = (short)f2bf(tile[r * 64 + (((crow >> 2) ^ ((r >> 3) & 15)) << 2) + (crow & 3)]);
    }
    *(bf16x8*)&dst[base + (size_t)(c0 + crow) * R + r0 + r8] = o;
  }
}

// ---------------- router (+ fused x->bf16): one wave per token ----------------
__global__ void router_kernel(const float* __restrict__ x, const float* __restrict__ Wr,
                              int* __restrict__ cnt, int* __restrict__ te,
                              float* __restrict__ tw, uint16_t* __restrict__ xb) {
  int wid = (blockIdx.x * blockDim.x + threadIdx.x) >> 6;
  int lane = threadIdx.x & 63;
  if (wid >= N_TOK) return;
  const float* xr = x + (size_t)wid * CDIM;
  uint16_t* xbr = xb + (size_t)wid * CDIM;
  float p[NEXP];
#pragma unroll
  for (int e = 0; e < NEXP; e++) p[e] = 0.f;
  for (int kk = 0; kk < CDIM / 64; kk++) {
    float xv = xr[kk * 64 + lane];
    xbr[kk * 64 + lane] = f2bf(xv);
#pragma unroll
    for (int e = 0; e < NEXP; e++)
      p[e] += xv * Wr[e * CDIM + kk * 64 + lane];
  }
#pragma unroll
  for (int e = 0; e < NEXP; e++) {
    float v = p[e];
#pragma unroll
    for (int s = 32; s > 0; s >>= 1) v += __shfl_xor(v, s);
    p[e] = v;
  }
  if (lane == 0) {
    float m0 = -1e30f, m1 = -1e30f; int i0 = 0, i1 = 0;
#pragma unroll
    for (int e = 0; e < NEXP; e++) {
      float v = p[e];
      if (v > m0) { m1 = m0; i1 = i0; m0 = v; i0 = e; }
      else if (v > m1) { m1 = v; i1 = e; }
    }
    float w0 = 1.f / (1.f + __expf(m1 - m0));
    te[wid] = i0 | (i1 << 16);
    tw[wid] = w0;
    atomicAdd(&cnt[i0], 1);
    atomicAdd(&cnt[i1], 1);
  }
}

// ---- prefix + compact work-list: wk[i] = (e<<16)|rb_block for every active 128-row block ----
__global__ void prefix_kernel(const int* __restrict__ cnt, int* __restrict__ offs,
                              int* __restrict__ fill, int* __restrict__ wk,
                              int* __restrict__ nwk) {
  if (threadIdx.x == 0) {
    int acc = 0, np = 0;
    for (int e = 0; e < NEXP; e++) {
      offs[e] = acc; fill[e] = acc;
      int nb = (cnt[e] + BM - 1) / BM;
      for (int r = 0; r < nb; r++) wk[np++] = (e << 16) | r;
      acc += cnt[e];
    }
    offs[NEXP] = acc;
    nwk[0] = np;
  }
}

__global__ void bucket_kernel(const int* __restrict__ te, const float* __restrict__ tw,
                              int* __restrict__ fill, int* __restrict__ perm,
                              float* __restrict__ pw) {
  int t = blockIdx.x * 256 + threadIdx.x;
  if (t >= N_TOK) return;
  int e01 = te[t];
  int e0 = e01 & 0xffff, e1 = e01 >> 16;
  float w0 = tw[t];
  int p0 = atomicAdd(&fill[e0], 1);
  perm[p0] = t; pw[p0] = w0;
  int p1 = atomicAdd(&fill[e1], 1);
  perm[p1] = t; pw[p1] = 1.f - w0;
}

// ---- grouped GEMM, TLP-maximal: 128x128, BK=64, SINGLE-buffered 32KB LDS -> 4 blocks/CU.
// ---- Serial per block {STG -> sync -> compute -> sync}; latency hidden by 4 independent
// ---- blocks/CU. slot^(row&7) XOR swizzle (8 slots @ 128B rows -> bank 4*perm, 2 lanes/
// ---- 4-bank group = conflict-free; r3-verified 0 conflicts). Grid ~= 1 block/item.
template<bool GATHER, bool RELU2, int NDIM, int KDIM>
__global__ __launch_bounds__(256, 4)
void moe_gemm(const uint16_t* __restrict__ A, const uint16_t* __restrict__ Bt,
              const int* __restrict__ offs, const int* __restrict__ wk,
              const int* __restrict__ nwk, const int* __restrict__ perm,
              const float* __restrict__ pw, uint16_t* __restrict__ hb,
              float* __restrict__ out) {
  const int NB = NDIM / BN;
  int nitems = nwk[0] * NB;
  int G = gridDim.x;
  int bid = blockIdx.x;
  int b0 = (bid & 7) * (G >> 3) + (bid >> 3);   // XCD gets contiguous item chunk

  __shared__ uint16_t smA[BM * BK];   // 16KB
  __shared__ uint16_t smB[BN * BK];   // 16KB   (32KB total)

  int tid = threadIdx.x;
  int w = tid >> 6, l = tid & 63;
  int wr = w >> 1, wc = w & 1;           // 2x2 waves, wave tile 64x64
  int cl = l & 15, kh = l >> 4;
  int rg = kh * 4;

  for (int item = b0; item < nitems; item += G) {
    int pi = item / NB, nb = item - pi * NB;
    int pr = wk[pi];
    int e = pr >> 16;
    int rb = (pr & 0xffff) * BM;
    int o0 = offs[e];
    int Me = offs[e + 1] - o0;
    int nb0 = nb * BN;

    // staging pointers: chunk c = j*256+tid -> row = c>>3 (32 rows/j), slot16B = c&7;
    // source k-chunk = slot ^ (row&7)  (XOR swizzle folded into source, linear LDS dest)
    const uint16_t* aptr[4];
#pragma unroll
    for (int j = 0; j < 4; j++) {
      int c = j * 256 + tid;
      int row = c >> 3, slot = c & 7;
      int gi = o0 + rb + row;
      if (gi > 2 * N_TOK - 1) gi = 2 * N_TOK - 1;
      int ar = GATHER ? perm[gi] : gi;
      aptr[j] = A + (size_t)ar * KDIM + ((slot ^ (row & 7)) << 3);
    }
    const uint16_t* bb = Bt + (size_t)e * NDIM * KDIM;
    const uint16_t* bptr[4];
#pragma unroll
    for (int j = 0; j < 4; j++) {
      int c = j * 256 + tid;
      int row = c >> 3, slot = c & 7;
      bptr[j] = bb + (size_t)(nb0 + row) * KDIM + ((slot ^ (row & 7)) << 3);
    }

    f32x4 acc[4][4];
#pragma unroll
    for (int m = 0; m < 4; m++)
#pragma unroll
      for (int n = 0; n < 4; n++)
        acc[m][n] = (f32x4)0.f;

    // swizzled frag read: 16B slot s XOR'd by row&7
#define LDSF(base, row, s) \
    (*(const bf16x8*)&(base)[(row) * BK + ((((s) ^ ((row) & 7))) << 3)])

    const int NT = KDIM / BK;
    for (int t = 0; t < NT; ++t) {
#pragma unroll
      for (int j = 0; j < 4; j++) {
        gload_lds16(aptr[j] + t * BK, (char*)&smA[0] + j * 4096 + tid * 16);
        gload_lds16(bptr[j] + t * BK, (char*)&smB[0] + j * 4096 + tid * 16);
      }
      __syncthreads();   // vmcnt(0)+lgkmcnt(0)+barrier: tile fully staged

      bf16x8 af[4][2], bf[4][2];
#pragma unroll
      for (int n = 0; n < 4; n++)
#pragma unroll
        for (int kk = 0; kk < 2; kk++)
          bf[n][kk] = LDSF(smB, wc * 64 + n * 16 + cl, kk * 4 + kh);
#pragma unroll
      for (int m = 0; m < 4; m++)
#pragma unroll
        for (int kk = 0; kk < 2; kk++)
          af[m][kk] = LDSF(smA, wr * 64 + m * 16 + cl, kk * 4 + kh);
#pragma unroll
      for (int m = 0; m < 4; m++)
#pragma unroll
        for (int n = 0; n < 4; n++) {
          acc[m][n] = __builtin_amdgcn_mfma_f32_16x16x32_bf16(af[m][0], bf[n][0], acc[m][n], 0, 0, 0);
          acc[m][n] = __builtin_amdgcn_mfma_f32_16x16x32_bf16(af[m][1], bf[n][1], acc[m][n], 0, 0, 0);
        }
      __syncthreads();   // reads done before next tile's staging overwrites
    }
#undef LDSF

    if (RELU2) {
#pragma unroll
      for (int m = 0; m < 4; m++) {
#pragma unroll
        for (int jj = 0; jj < 4; jj++) {
          int er = rb + wr * 64 + m * 16 + rg + jj;
          if (er < Me) {
            size_t rowoff = (size_t)(o0 + er) * NDIM;
#pragma unroll
            for (int n = 0; n < 4; n++) {
              int gc = nb0 + wc * 64 + n * 16 + cl;
              float v = acc[m][n][jj];
              v = v > 0.f ? v * v : 0.f;
              hb[rowoff + gc] = f2bf(v);
            }
          }
        }
      }
    } else {
#pragma unroll
      for (int m = 0; m < 4; m++) {
#pragma unroll
        for (int jj = 0; jj < 4; jj++) {
          int er = rb + wr * 64 + m * 16 + rg + jj;
          if (er < Me) {
            int gi = o0 + er;
            int tok = perm[gi];
            float wgt = pw[gi];
            size_t rowoff = (size_t)tok * NDIM;
#pragma unroll
            for (int n = 0; n < 4; n++) {
              int gc = nb0 + wc * 64 + n * 16 + cl;
              atomicAdd(&out[rowoff + gc], wgt * acc[m][n][jj]);
            }
          }
        }
      }
    }
  }
}

extern "C" void kernel_launch(void* const* d_in, const int* in_sizes, int n_in,
                              void* d_out, int out_size, void* d_ws, size_t ws_size,
                              hipStream_t stream) {
  const float* x  = (const float*)d_in[0];
  const float* Wr = (const float*)d_in[1];
  const float* W1 = (const float*)d_in[2];
  const float* W2 = (const float*)d_in[3];
  float* out = (float*)d_out;

  char* ws = (char*)d_ws;
  size_t off = 0;
  uint16_t* xb  = (uint16_t*)(ws + off); off += (size_t)N_TOK * CDIM * 2;
  uint16_t* W1t = (uint16_t*)(ws + off); off += (size_t)NEXP * CDIM * HDIM * 2;
  uint16_t* W2t = (uint16_t*)(ws + off); off += (size_t)NEXP * CDIM * HDIM * 2;
  uint16_t* hb  = (uint16_t*)(ws + off); off += (size_t)2 * N_TOK * HDIM * 2;
  int*   perm = (int*)(ws + off); off += (size_t)2 * N_TOK * 4;
  float* pwt  = (float*)(ws + off); off += (size_t)2 * N_TOK * 4;
  int*   te   = (int*)(ws + off); off += (size_t)N_TOK * 4;
  float* tw   = (float*)(ws + off); off += (size_t)N_TOK * 4;
  int*   cnt  = (int*)(ws + off); off += 16 * 4;
  int*   offs = (int*)(ws + off); off += 16 * 4;
  int*   fill = (int*)(ws + off); off += 16 * 4;
  int*   wk   = (int*)(ws + off); off += 256 * 4;
  int*   nwk  = (int*)(ws + off); off += 16 * 4;

  hipMemsetAsync(d_out, 0, (size_t)out_size * sizeof(float), stream);
  hipMemsetAsync(cnt, 0, 16 * 4, stream);

  router_kernel<<<N_TOK / 4, 256, 0, stream>>>(x, Wr, cnt, te, tw, xb);
  transcvt_kernel<<<dim3(HDIM / 64, CDIM / 128, NEXP), 256, 0, stream>>>(W1, W1t, CDIM, HDIM);
  transcvt_kernel<<<dim3(CDIM / 64, HDIM / 128, NEXP), 256, 0, stream>>>(W2, W2t, HDIM, CDIM);
  prefix_kernel<<<1, 64, 0, stream>>>(cnt, offs, fill, wk, nwk);
  bucket_kernel<<<N_TOK / 256, 256, 0, stream>>>(te, tw, fill, perm, pwt);

  // GEMM1: h = relu^2(x @ W1)  [rows gathered via perm]  items ~= 4096-4320 -> ~1/block
  moe_gemm<true, true, HDIM, CDIM><<<4352, 256, 0, stream>>>(
      xb, W1t, offs, wk, nwk, perm, pwt, hb, out);
  // GEMM2: out += gate * (h @ W2)   items ~= 1024-1080 -> ~1/block
  moe_gemm<false, false, CDIM, HDIM><<<1088, 256, 0, stream>>>(
      hb, W2t, offs, wk, nwk, perm, pwt, hb, out);
}